// Round 3
// baseline (754.743 us; speedup 1.0000x reference)
//
#include <hip/hip_runtime.h>

// LSTM_52922587021316 — Round 3: MFMA f16 + prescaled-gate activations.
// vs R2: (1) weights/biases prescaled by -log2e (i,f,o) / 2*log2e (g) so
// sigmoid = rcp(1+exp2(s)), tanh = 1-2*rcp(exp2(s)+1) — no clamps, no muls,
// NaN-free at +/-inf. (2) no manual lgkmcnt fences (same-wave DS is in-order;
// compiler inserts minimal waits before fragment use). (3) x staged through
// LDS transposed -> per-t ds_read_b128 instead of 4 scattered global loads.
// (4) rank-1 x-term folded into accumulator init. (5) launch_bounds(256,4).

#define HID 32
#define TSTEPS 7
#define LSTRIDE 40   // halves per LDS h-row: 32 + 8 pad (80 B, 16B-aligned)

typedef _Float16 half8 __attribute__((ext_vector_type(8)));
typedef float floatx4 __attribute__((ext_vector_type(4)));

#define LOG2E 1.44269504088896f

__device__ __forceinline__ float fast_rcp(float x) { return __builtin_amdgcn_rcpf(x); }

__device__ __forceinline__ float exp2_fast(float x) {
#if __has_builtin(__builtin_amdgcn_exp2f)
    return __builtin_amdgcn_exp2f(x);
#else
    return __expf(x * 0.69314718055994531f);
#endif
}

// s = -x*log2e already applied via weight prescale
__device__ __forceinline__ float sigm_pre(float s) {
    return fast_rcp(1.0f + exp2_fast(s));
}
// s = 2x*log2e already applied via weight prescale
__device__ __forceinline__ float tanh_pre(float s) {
    return fmaf(-2.0f, fast_rcp(exp2_fast(s) + 1.0f), 1.0f);
}
// raw argument (cell state c)
__device__ __forceinline__ float tanh_raw(float x) {
    return tanh_pre(x * (2.0f * LOG2E));
}

__global__ __launch_bounds__(256, 4) void lstm2_mfma(
    const float* __restrict__ xin,   // [B, 7]
    const float* __restrict__ Wih0,  // [128, 1]
    const float* __restrict__ Whh0,  // [128, 32]
    const float* __restrict__ bih0,  // [128]
    const float* __restrict__ bhh0,  // [128]
    const float* __restrict__ Wih1,  // [128, 32]
    const float* __restrict__ Whh1,  // [128, 32]
    const float* __restrict__ bih1,  // [128]
    const float* __restrict__ bhh1,  // [128]
    const float* __restrict__ fcw,   // [32]
    const float* __restrict__ fcb,   // [1]
    const float* __restrict__ fc1w,  // [7]
    const float* __restrict__ fc1b,  // [1]
    float* __restrict__ out,         // [B]
    int B)
{
    const int lane = threadIdx.x & 63;
    const int wave = threadIdx.x >> 6;
    const int col  = lane & 15;          // C col / A row m
    const int rg   = lane >> 4;          // C rows rg*4..+3 / A k-chunk rg*8..+7
    const int seq_base = (blockIdx.x * 4 + wave) * 16;

    __shared__ __align__(16) _Float16 ldsh[4][2][16 * LSTRIDE];
    __shared__ __align__(16) float ldsx[4][TSTEPS * 16];
    _Float16* h1l = &ldsh[wave][0][0];
    _Float16* h2l = &ldsh[wave][1][0];
    float* xl = &ldsx[wave][0];

    // ---- stage x: 112 contiguous floats per wave -> transposed [t][seq] ---
#pragma unroll
    for (int e = lane; e < TSTEPS * 16; e += 64) {
        const int s = e / TSTEPS;
        const int tt = e - s * TSTEPS;
        xl[tt * 16 + s] = xin[seq_base * TSTEPS + e];
    }
    // same-wave DS in-order; read below waits via compiler lgkmcnt

    // ---- preload weights as prescaled f16 B-fragments ---------------------
    // b_frag[j] = scale(n) * W[n = nt*16+col][k = rg*8+j]
    half8 B0[8], B1a[8], B1b[8];
    float b0s[8], b1s[8], wx[8];
#pragma unroll
    for (int nt = 0; nt < 8; ++nt) {
        const int n = nt * 16 + col;
        const int gate = n >> 5;                       // 0=i 1=f 2=g 3=o
        const float sc = (gate == 2) ? (2.0f * LOG2E) : (-LOG2E);
        const float* s0 = Whh0 + n * HID + rg * 8;
        const float* s1 = Wih1 + n * HID + rg * 8;
        const float* s2 = Whh1 + n * HID + rg * 8;
#pragma unroll
        for (int j = 0; j < 8; ++j) {
            B0[nt][j]  = (_Float16)(sc * s0[j]);
            B1a[nt][j] = (_Float16)(sc * s1[j]);
            B1b[nt][j] = (_Float16)(sc * s2[j]);
        }
        b0s[nt] = sc * (bih0[n] + bhh0[n]);
        b1s[nt] = sc * (bih1[n] + bhh1[n]);
        wx[nt]  = sc * Wih0[n];
    }
    const float fcw_l0 = fcw[col];
    const float fcw_l1 = fcw[16 + col];

    half8 Ah1 = {};      // h1 in A-layout (zero at t=0)
    half8 Ah2 = {};      // h2 in A-layout
    float c1[2][4] = {}, c2[2][4] = {};
    float facc[4] = {0.f, 0.f, 0.f, 0.f};

#pragma unroll
    for (int t = 0; t < TSTEPS; ++t) {
        // x for my 4 C-rows (m = rg*4 + r): one b128, conflict-free broadcast
        const floatx4 xr = *(const floatx4*)&xl[t * 16 + rg * 4];

        // -------- layer 0: gates = (bias + x*Wih0) + h1_prev @ Whh0^T -----
        floatx4 g0[8];
#pragma unroll
        for (int nt = 0; nt < 8; ++nt) {
            floatx4 c;
#pragma unroll
            for (int r = 0; r < 4; ++r) c[r] = fmaf(wx[nt], xr[r], b0s[nt]);
            g0[nt] = __builtin_amdgcn_mfma_f32_16x16x32_f16(Ah1, B0[nt], c, 0, 0, 0);
        }

        // epilogue 0: cell update, write h1_new to LDS
#pragma unroll
        for (int q = 0; q < 2; ++q) {
#pragma unroll
            for (int r = 0; r < 4; ++r) {
                const float ii = sigm_pre(g0[0 + q][r]);
                const float ff = sigm_pre(g0[2 + q][r]);
                const float gg = tanh_pre(g0[4 + q][r]);
                const float oo = sigm_pre(g0[6 + q][r]);
                const float c  = ff * c1[q][r] + ii * gg;
                c1[q][r] = c;
                const float h = oo * tanh_raw(c);
                h1l[(rg * 4 + r) * LSTRIDE + q * 16 + col] = (_Float16)h;
            }
        }
        Ah1 = *(const half8*)&h1l[col * LSTRIDE + rg * 8];

        // -------- layer 1: gates = bias + h1_new @ Wih1^T + h2_prev @ Whh1^T
        floatx4 g1[8];
#pragma unroll
        for (int nt = 0; nt < 8; ++nt) {
            floatx4 c = {b1s[nt], b1s[nt], b1s[nt], b1s[nt]};
            c = __builtin_amdgcn_mfma_f32_16x16x32_f16(Ah1, B1a[nt], c, 0, 0, 0);
            g1[nt] = __builtin_amdgcn_mfma_f32_16x16x32_f16(Ah2, B1b[nt], c, 0, 0, 0);
        }

        // epilogue 1: cell update, fc partial, write h2_new to LDS
        const float f1t = fc1w[t];
        const float w0 = f1t * fcw_l0;
        const float w1 = f1t * fcw_l1;
#pragma unroll
        for (int q = 0; q < 2; ++q) {
            const float wq = q ? w1 : w0;
#pragma unroll
            for (int r = 0; r < 4; ++r) {
                const float ii = sigm_pre(g1[0 + q][r]);
                const float ff = sigm_pre(g1[2 + q][r]);
                const float gg = tanh_pre(g1[4 + q][r]);
                const float oo = sigm_pre(g1[6 + q][r]);
                const float c  = ff * c2[q][r] + ii * gg;
                c2[q][r] = c;
                const float h = oo * tanh_raw(c);
                facc[r] = fmaf(wq, h, facc[r]);
                h2l[(rg * 4 + r) * LSTRIDE + q * 16 + col] = (_Float16)h;
            }
        }
        Ah2 = *(const half8*)&h2l[col * LSTRIDE + rg * 8];
    }

    // ---- reduce fc partials across the 16 cols, add constant tail --------
#pragma unroll
    for (int r = 0; r < 4; ++r) {
        float v = facc[r];
        v += __shfl_xor(v, 1);
        v += __shfl_xor(v, 2);
        v += __shfl_xor(v, 4);
        v += __shfl_xor(v, 8);
        facc[r] = v;
    }
    float sum_f1 = 0.f;
#pragma unroll
    for (int t = 0; t < TSTEPS; ++t) sum_f1 += fc1w[t];
    const float tail = fcb[0] * sum_f1 + fc1b[0];

    if (col == 0) {
#pragma unroll
        for (int r = 0; r < 4; ++r)
            out[seq_base + rg * 4 + r] = facc[r] + tail;
    }
}

extern "C" void kernel_launch(void* const* d_in, const int* in_sizes, int n_in,
                              void* d_out, int out_size, void* d_ws, size_t ws_size,
                              hipStream_t stream) {
    const float* xin  = (const float*)d_in[0];
    const float* Wih0 = (const float*)d_in[1];
    const float* Whh0 = (const float*)d_in[2];
    const float* bih0 = (const float*)d_in[3];
    const float* bhh0 = (const float*)d_in[4];
    const float* Wih1 = (const float*)d_in[5];
    const float* Whh1 = (const float*)d_in[6];
    const float* bih1 = (const float*)d_in[7];
    const float* bhh1 = (const float*)d_in[8];
    const float* fcw  = (const float*)d_in[9];
    const float* fcb  = (const float*)d_in[10];
    const float* fc1w = (const float*)d_in[11];
    const float* fc1b = (const float*)d_in[12];
    float* out = (float*)d_out;

    const int B = in_sizes[0] / TSTEPS;   // [B, T, F=1]
    const int grid = B / 64;              // 1 block = 4 waves = 64 sequences
    lstm2_mfma<<<grid, 256, 0, stream>>>(
        xin, Wih0, Whh0, bih0, bhh0, Wih1, Whh1, bih1, bhh1,
        fcw, fcb, fc1w, fc1b, out, B);
}

// Round 4
// 269.139 us; speedup vs baseline: 2.8043x; 2.8043x over previous
//
#include <hip/hip_runtime.h>

// LSTM_52922587021316 — Round 4: R3 minus the spill-inducer.
// R3's launch_bounds(256,4)+full t-unroll capped VGPRs at 64 -> 96-VGPR
// weight fragments spilled to scratch (FETCH 3.8MB->1.7GB, dur 224->726us).
// This round: launch_bounds(256,2) (R2's setting, 124 VGPR, no spill),
// compiler-chosen t-loop unrolling. Keeps R3's wins: prescaled-gate
// activations (sigmoid=rcp(1+exp2(s)), tanh=1-2*rcp(exp2(s)+1), no clamps),
// x staged through LDS transposed, rank-1 x-term in accumulator init,
// no manual lgkmcnt fences.

#define HID 32
#define TSTEPS 7
#define LSTRIDE 40   // halves per LDS h-row: 32 + 8 pad (80 B, 16B-aligned)

typedef _Float16 half8 __attribute__((ext_vector_type(8)));
typedef float floatx4 __attribute__((ext_vector_type(4)));

#define LOG2E 1.44269504088896f

__device__ __forceinline__ float fast_rcp(float x) { return __builtin_amdgcn_rcpf(x); }

__device__ __forceinline__ float exp2_fast(float x) {
#if __has_builtin(__builtin_amdgcn_exp2f)
    return __builtin_amdgcn_exp2f(x);
#else
    return __expf(x * 0.69314718055994531f);
#endif
}

// s = -x*log2e already applied via weight prescale
__device__ __forceinline__ float sigm_pre(float s) {
    return fast_rcp(1.0f + exp2_fast(s));
}
// s = 2x*log2e already applied via weight prescale
__device__ __forceinline__ float tanh_pre(float s) {
    return fmaf(-2.0f, fast_rcp(exp2_fast(s) + 1.0f), 1.0f);
}
// raw argument (cell state c)
__device__ __forceinline__ float tanh_raw(float x) {
    return tanh_pre(x * (2.0f * LOG2E));
}

__global__ __launch_bounds__(256, 2) void lstm2_mfma(
    const float* __restrict__ xin,   // [B, 7]
    const float* __restrict__ Wih0,  // [128, 1]
    const float* __restrict__ Whh0,  // [128, 32]
    const float* __restrict__ bih0,  // [128]
    const float* __restrict__ bhh0,  // [128]
    const float* __restrict__ Wih1,  // [128, 32]
    const float* __restrict__ Whh1,  // [128, 32]
    const float* __restrict__ bih1,  // [128]
    const float* __restrict__ bhh1,  // [128]
    const float* __restrict__ fcw,   // [32]
    const float* __restrict__ fcb,   // [1]
    const float* __restrict__ fc1w,  // [7]
    const float* __restrict__ fc1b,  // [1]
    float* __restrict__ out,         // [B]
    int B)
{
    const int lane = threadIdx.x & 63;
    const int wave = threadIdx.x >> 6;
    const int col  = lane & 15;          // C col / A row m
    const int rg   = lane >> 4;          // C rows rg*4..+3 / A k-chunk rg*8..+7
    const int seq_base = (blockIdx.x * 4 + wave) * 16;

    __shared__ __align__(16) _Float16 ldsh[4][2][16 * LSTRIDE];
    __shared__ __align__(16) float ldsx[4][TSTEPS * 16];
    _Float16* h1l = &ldsh[wave][0][0];
    _Float16* h2l = &ldsh[wave][1][0];
    float* xl = &ldsx[wave][0];

    // ---- stage x: 112 contiguous floats per wave -> transposed [t][seq] ---
#pragma unroll
    for (int e = lane; e < TSTEPS * 16; e += 64) {
        const int s = e / TSTEPS;
        const int tt = e - s * TSTEPS;
        xl[tt * 16 + s] = xin[seq_base * TSTEPS + e];
    }
    // same-wave DS in-order; reads below wait via compiler-inserted lgkmcnt

    // ---- preload weights as prescaled f16 B-fragments ---------------------
    // b_frag[j] = scale(n) * W[n = nt*16+col][k = rg*8+j]
    half8 B0[8], B1a[8], B1b[8];
    float b0s[8], b1s[8], wx[8];
#pragma unroll
    for (int nt = 0; nt < 8; ++nt) {
        const int n = nt * 16 + col;
        const int gate = n >> 5;                       // 0=i 1=f 2=g 3=o
        const float sc = (gate == 2) ? (2.0f * LOG2E) : (-LOG2E);
        const float* s0 = Whh0 + n * HID + rg * 8;
        const float* s1 = Wih1 + n * HID + rg * 8;
        const float* s2 = Whh1 + n * HID + rg * 8;
#pragma unroll
        for (int j = 0; j < 8; ++j) {
            B0[nt][j]  = (_Float16)(sc * s0[j]);
            B1a[nt][j] = (_Float16)(sc * s1[j]);
            B1b[nt][j] = (_Float16)(sc * s2[j]);
        }
        b0s[nt] = sc * (bih0[n] + bhh0[n]);
        b1s[nt] = sc * (bih1[n] + bhh1[n]);
        wx[nt]  = sc * Wih0[n];
    }
    const float fcw_l0 = fcw[col];
    const float fcw_l1 = fcw[16 + col];

    half8 Ah1 = {};      // h1 in A-layout (zero at t=0)
    half8 Ah2 = {};      // h2 in A-layout
    float c1[2][4] = {}, c2[2][4] = {};
    float facc[4] = {0.f, 0.f, 0.f, 0.f};

    for (int t = 0; t < TSTEPS; ++t) {
        // x for my 4 C-rows (m = rg*4 + r): one b128, conflict-free broadcast
        const floatx4 xr = *(const floatx4*)&xl[t * 16 + rg * 4];

        // -------- layer 0: gates = (bias + x*Wih0) + h1_prev @ Whh0^T -----
        floatx4 g0[8];
#pragma unroll
        for (int nt = 0; nt < 8; ++nt) {
            floatx4 c;
#pragma unroll
            for (int r = 0; r < 4; ++r) c[r] = fmaf(wx[nt], xr[r], b0s[nt]);
            g0[nt] = __builtin_amdgcn_mfma_f32_16x16x32_f16(Ah1, B0[nt], c, 0, 0, 0);
        }

        // epilogue 0: cell update, write h1_new to LDS
#pragma unroll
        for (int q = 0; q < 2; ++q) {
#pragma unroll
            for (int r = 0; r < 4; ++r) {
                const float ii = sigm_pre(g0[0 + q][r]);
                const float ff = sigm_pre(g0[2 + q][r]);
                const float gg = tanh_pre(g0[4 + q][r]);
                const float oo = sigm_pre(g0[6 + q][r]);
                const float c  = ff * c1[q][r] + ii * gg;
                c1[q][r] = c;
                const float h = oo * tanh_raw(c);
                h1l[(rg * 4 + r) * LSTRIDE + q * 16 + col] = (_Float16)h;
            }
        }
        Ah1 = *(const half8*)&h1l[col * LSTRIDE + rg * 8];

        // -------- layer 1: gates = bias + h1_new @ Wih1^T + h2_prev @ Whh1^T
        floatx4 g1[8];
#pragma unroll
        for (int nt = 0; nt < 8; ++nt) {
            floatx4 c = {b1s[nt], b1s[nt], b1s[nt], b1s[nt]};
            c = __builtin_amdgcn_mfma_f32_16x16x32_f16(Ah1, B1a[nt], c, 0, 0, 0);
            g1[nt] = __builtin_amdgcn_mfma_f32_16x16x32_f16(Ah2, B1b[nt], c, 0, 0, 0);
        }

        // epilogue 1: cell update, fc partial, write h2_new to LDS
        const float f1t = fc1w[t];
        const float w0 = f1t * fcw_l0;
        const float w1 = f1t * fcw_l1;
#pragma unroll
        for (int q = 0; q < 2; ++q) {
            const float wq = q ? w1 : w0;
#pragma unroll
            for (int r = 0; r < 4; ++r) {
                const float ii = sigm_pre(g1[0 + q][r]);
                const float ff = sigm_pre(g1[2 + q][r]);
                const float gg = tanh_pre(g1[4 + q][r]);
                const float oo = sigm_pre(g1[6 + q][r]);
                const float c  = ff * c2[q][r] + ii * gg;
                c2[q][r] = c;
                const float h = oo * tanh_raw(c);
                facc[r] = fmaf(wq, h, facc[r]);
                h2l[(rg * 4 + r) * LSTRIDE + q * 16 + col] = (_Float16)h;
            }
        }
        Ah2 = *(const half8*)&h2l[col * LSTRIDE + rg * 8];
    }

    // ---- reduce fc partials across the 16 cols, add constant tail --------
#pragma unroll
    for (int r = 0; r < 4; ++r) {
        float v = facc[r];
        v += __shfl_xor(v, 1);
        v += __shfl_xor(v, 2);
        v += __shfl_xor(v, 4);
        v += __shfl_xor(v, 8);
        facc[r] = v;
    }
    float sum_f1 = 0.f;
#pragma unroll
    for (int t = 0; t < TSTEPS; ++t) sum_f1 += fc1w[t];
    const float tail = fcb[0] * sum_f1 + fc1b[0];

    if (col == 0) {
#pragma unroll
        for (int r = 0; r < 4; ++r)
            out[seq_base + rg * 4 + r] = facc[r] + tail;
    }
}

extern "C" void kernel_launch(void* const* d_in, const int* in_sizes, int n_in,
                              void* d_out, int out_size, void* d_ws, size_t ws_size,
                              hipStream_t stream) {
    const float* xin  = (const float*)d_in[0];
    const float* Wih0 = (const float*)d_in[1];
    const float* Whh0 = (const float*)d_in[2];
    const float* bih0 = (const float*)d_in[3];
    const float* bhh0 = (const float*)d_in[4];
    const float* Wih1 = (const float*)d_in[5];
    const float* Whh1 = (const float*)d_in[6];
    const float* bih1 = (const float*)d_in[7];
    const float* bhh1 = (const float*)d_in[8];
    const float* fcw  = (const float*)d_in[9];
    const float* fcb  = (const float*)d_in[10];
    const float* fc1w = (const float*)d_in[11];
    const float* fc1b = (const float*)d_in[12];
    float* out = (float*)d_out;

    const int B = in_sizes[0] / TSTEPS;   // [B, T, F=1]
    const int grid = B / 64;              // 1 block = 4 waves = 64 sequences
    lstm2_mfma<<<grid, 256, 0, stream>>>(
        xin, Wih0, Whh0, bih0, bhh0, Wih1, Whh1, bih1, bhh1,
        fcw, fcb, fc1w, fc1b, out, B);
}